// Round 9
// baseline (173.118 us; speedup 1.0000x reference)
//
#include <hip/hip_runtime.h>

// B(derived), IN_DIM=784, NUM_NETS=30, N_NODES=20, NUM_OUT=10, DIM_OUT=16, NUM_ITER=3
// Validated: size-based binding; k1m MFMA BK=64 (R22 LDS-staged epilogue); k2w fused
// u+priors MFMA w/ coalesced n-major pri store; k3w routing w/ LDS-broadcast allgather.
// R23: kill the xb staging buffer -- k1m reads x DIRECTLY (bf16 or fp32->bf16 inline in
// the staging loop; conversion hides under barrier latency). Dtype flag plumbed via ws:
// prep block 0 publishes its per-block flags to global; k1m reads flags[0] at entry
// (1 load + the existing barrier). detect_dtype launch deleted (k2s reads prep's flags).
// prep drops the x section (1.6M threads) and skips rwb in mode 0 (96K threads):
// 2.3M -> 0.3M threads, -38MB HBM (x-read + xb-write + xb-read). Tail k0=768: aseg=0
// covers 768..783 (valid), aseg=1 covers 784..799 (pad) -> zeros, == old xb padding.
// Fallback k2s+k3y2 unchanged.

typedef unsigned short bfu;
typedef unsigned int u32;
typedef __attribute__((ext_vector_type(8))) short short8;
typedef __attribute__((ext_vector_type(4))) float floatx4;

__device__ __forceinline__ float bf2f(bfu u) { union { u32 i; float f; } v; v.i = ((u32)u) << 16; return v.f; }
__device__ __forceinline__ float lo2f(u32 w) { union { u32 i; float f; } v; v.i = w << 16; return v.f; }
__device__ __forceinline__ float hi2f(u32 w) { union { u32 i; float f; } v; v.i = w & 0xffff0000u; return v.f; }
__device__ __forceinline__ float ldf(const void* p, int idx, bool b16) {
    return b16 ? bf2f(((const bfu*)p)[idx]) : ((const float*)p)[idx];
}
__device__ __forceinline__ bfu f2bf(float f) {   // RNE
    u32 u = __float_as_uint(f);
    return (bfu)((u + 0x7FFFu + ((u >> 16) & 1u)) >> 16);
}
__device__ __forceinline__ void unpack8(uint4 q, float* dst) {
    dst[0] = lo2f(q.x); dst[1] = hi2f(q.x);
    dst[2] = lo2f(q.y); dst[3] = hi2f(q.y);
    dst[4] = lo2f(q.z); dst[5] = hi2f(q.z);
    dst[6] = lo2f(q.w); dst[7] = hi2f(q.w);
}
__device__ __forceinline__ uint4 pack8(const float* p) {   // 8 f32 -> 8 bf16 (RNE)
    float4 a = *(const float4*)p, b = *(const float4*)(p + 4);
    uint4 q;
    q.x = (u32)f2bf(a.x) | ((u32)f2bf(a.y) << 16);
    q.y = (u32)f2bf(a.z) | ((u32)f2bf(a.w) << 16);
    q.z = (u32)f2bf(b.x) | ((u32)f2bf(b.y) << 16);
    q.w = (u32)f2bf(b.z) | ((u32)f2bf(b.w) << 16);
    return q;
}
__device__ __forceinline__ u32 detect_one(const u32* p) {
    int c = 0;
    for (int i = 0; i < 64; i++) {
        u32 e = (p[i] >> 7) & 0xFF;
        c += (e >= 64 && e <= 140) ? 1 : 0;
    }
    return (c >= 48) ? 1u : 0u;
}

// ---- prep_all (R23): Wt4 | b1f | (rwn|W2t|b2f if mode==0 else rwb); self-detecting;
//      block 0 publishes flags to global (consumed by k1m and fallback k2s). ----
__global__ void prep_all(const void* x, const void* W1, const void* b1,
                         const void* W2, const void* b2, const void* rw,
                         bfu* __restrict__ Wt, float* __restrict__ b1f,
                         bfu* __restrict__ rwb, bfu* __restrict__ rwn,
                         float* __restrict__ W2t, float* __restrict__ b2f,
                         u32* __restrict__ flags_g, int mode) {
    __shared__ u32 flg[6];
    {
        const int t = threadIdx.x;
        if (t < 6) {
            const u32* p = (t == 0) ? (const u32*)x : (t == 1) ? (const u32*)W1
                         : (t == 2) ? (const u32*)b1 : (t == 3) ? (const u32*)W2
                         : (t == 4) ? (const u32*)b2 : (const u32*)rw;
            flg[t] = detect_one(p);
        }
    }
    __syncthreads();
    if (blockIdx.x == 0 && threadIdx.x < 6) flags_g[threadIdx.x] = flg[threadIdx.x];

    int i2 = blockIdx.x * 256 + threadIdx.x;
    if (i2 < 128000) {                                 // Wt[c][k] bf16, 4/thread
        const bool wb = flg[1] != 0;
        int c = i2 / 200, k = (i2 - c * 200) * 4;
        ushort4 w; w.x = 0; w.y = 0; w.z = 0; w.w = 0;
        if (c < 600 && k < 784) {
            int nn = c / 20, o = c - nn * 20;
            int src = nn * 15680 + k * 20 + o;         // k-stride 20
            if (wb) {
                const bfu* p = (const bfu*)W1;
                w.x = p[src]; w.y = p[src + 20]; w.z = p[src + 40]; w.w = p[src + 60];
            } else {
                const float* p = (const float*)W1;
                w.x = f2bf(p[src]); w.y = f2bf(p[src + 20]);
                w.z = f2bf(p[src + 40]); w.w = f2bf(p[src + 60]);
            }
        }
        *(ushort4*)(Wt + c * 800 + k) = w;
        return;
    }
    i2 -= 128000;
    if (i2 < 640) {                                    // b1f fp32
        b1f[i2] = (i2 < 600) ? ldf(b1, i2, flg[2] != 0) : 0.f;
        return;
    }
    i2 -= 640;
    if (mode == 0) {
        if (i2 < 153600) {                             // rwn[n][col=o*16+k][dd<32] bf16, K-pad
            const bool rb = flg[5] != 0;
            int dd = i2 % 32;
            int col = (i2 / 32) % 160;
            int n = i2 / 5120;
            bfu v = 0;
            if (dd < 20) {
                int o = col / 16, kk = col % 16;
                int src = o * 9600 + n * 320 + dd * 16 + kk;
                v = rb ? ((const bfu*)rw)[src] : f2bf(((const float*)rw)[src]);
            }
            rwn[i2] = v;
            return;
        }
        i2 -= 153600;
        if (i2 < 12000) {                              // W2t[n][e][d] fp32 = W2[n][d][e]
            int d = i2 % 20;
            int e = (i2 / 20) % 20;
            int n = i2 / 400;
            W2t[i2] = ldf(W2, n * 400 + d * 20 + e, flg[3] != 0);
            return;
        }
        i2 -= 12000;
        if (i2 < 640) {                                // b2f fp32
            b2f[i2] = (i2 < 600) ? ldf(b2, i2, flg[4] != 0) : 0.f;
        }
    } else {
        if (i2 < 96000) {                              // rwb[o][n][k][d] bf16 (fallback k3y2)
            const bool rb = flg[5] != 0;
            int d = i2 % 20;
            int k = (i2 / 20) % 16;
            int n = (i2 / 320) % 30;
            int o = i2 / 9600;
            int src = o * 9600 + n * 320 + d * 16 + k;
            rwb[i2] = rb ? ((const bfu*)rw)[src] : f2bf(((const float*)rw)[src]);
        }
    }
}

// ---------------- K1m (R23): h1 = relu(x @ Wt^T + b1), reads x directly ----------------
// tr==1 (mode 0): h1 [n][b][20], LDS-staged coalesced float4 stores. tr==0: [b][600] direct.
__global__ __launch_bounds__(256, 4) void k1m(const void* __restrict__ x, const bfu* __restrict__ Wt,
                                              const float* __restrict__ b1f, const u32* __restrict__ flags,
                                              float* __restrict__ h1, int Btot, int tr) {
    __shared__ __align__(16) char smem[128 * 68 * 4];   // max(As+Bs=27648, ep=34816)
    __shared__ u32 xflag;
    short* As = (short*)smem;                   // [128][72]
    short* Bs = (short*)(smem + 128 * 72 * 2);  // [64][72]
    const int tid = threadIdx.x;
    if (tid == 0) xflag = flags[0];
    const int w = tid >> 6, lane = tid & 63;
    const int quad = lane >> 4, fl = lane & 15;
    const int m0 = blockIdx.x * 128, n0 = blockIdx.y * 64;

    floatx4 acc[2][4];
    #pragma unroll
    for (int mi = 0; mi < 2; mi++)
        #pragma unroll
        for (int ni = 0; ni < 4; ni++) acc[mi][ni] = (floatx4){0.f, 0.f, 0.f, 0.f};

    const int arow = tid >> 1, aseg = tid & 1;    // 2 thr/row, 64B each
    const int brow = tid >> 2, bseg = tid & 3;    // 4 thr/row, 32B each
    int agrow = m0 + arow; if (agrow >= Btot) agrow = Btot - 1;
    const bfu*   xh = (const bfu*)x   + (size_t)agrow * 784;   // bf16 view
    const float* xf = (const float*)x + (size_t)agrow * 784;   // fp32 view
    const bfu* bbase = Wt + (size_t)(n0 + brow) * 800 + bseg * 16;

    __syncthreads();                       // xflag visible to all
    const bool xb16 = xflag != 0;

    // 12 steps of BK=64
    for (int k0 = 0; k0 < 768; k0 += 64) {
        uint4 qa0, qa1, qa2, qa3;
        if (xb16) {
            const bfu* p = xh + k0 + aseg * 32;
            qa0 = *(const uint4*)(p);
            qa1 = *(const uint4*)(p + 8);
            qa2 = *(const uint4*)(p + 16);
            qa3 = *(const uint4*)(p + 24);
        } else {
            const float* p = xf + k0 + aseg * 32;
            qa0 = pack8(p); qa1 = pack8(p + 8); qa2 = pack8(p + 16); qa3 = pack8(p + 24);
        }
        uint4 qb0 = *(const uint4*)(bbase + k0);
        uint4 qb1 = *(const uint4*)(bbase + k0 + 8);

        __syncthreads();
        *(uint4*)&As[arow * 72 + aseg * 32 + 0]  = qa0;
        *(uint4*)&As[arow * 72 + aseg * 32 + 8]  = qa1;
        *(uint4*)&As[arow * 72 + aseg * 32 + 16] = qa2;
        *(uint4*)&As[arow * 72 + aseg * 32 + 24] = qa3;
        *(uint4*)&Bs[brow * 72 + bseg * 16 + 0]  = qb0;
        *(uint4*)&Bs[brow * 72 + bseg * 16 + 8]  = qb1;
        __syncthreads();

        short8 af[2][2], bfr[4][2];
        #pragma unroll
        for (int mi = 0; mi < 2; mi++)
            #pragma unroll
            for (int kk = 0; kk < 2; kk++)
                af[mi][kk] = *(const short8*)&As[(w * 32 + mi * 16 + fl) * 72 + kk * 32 + quad * 8];
        #pragma unroll
        for (int ni = 0; ni < 4; ni++)
            #pragma unroll
            for (int kk = 0; kk < 2; kk++)
                bfr[ni][kk] = *(const short8*)&Bs[(ni * 16 + fl) * 72 + kk * 32 + quad * 8];
        #pragma unroll
        for (int kk = 0; kk < 2; kk++)
            #pragma unroll
            for (int mi = 0; mi < 2; mi++)
                #pragma unroll
                for (int ni = 0; ni < 4; ni++)
                    acc[mi][ni] = __builtin_amdgcn_mfma_f32_16x16x32_bf16(af[mi][kk], bfr[ni][kk], acc[mi][ni], 0, 0, 0);
    }

    // tail step: k0=768, 32 wide; aseg=0 -> elems 768..783 (valid), aseg=1 -> 784..799 (pad=0)
    {
        uint4 qa0, qa1;
        if (aseg == 0) {
            if (xb16) {
                qa0 = *(const uint4*)(xh + 768);
                qa1 = *(const uint4*)(xh + 776);
            } else {
                qa0 = pack8(xf + 768);
                qa1 = pack8(xf + 776);
            }
        } else {
            qa0 = (uint4){0u, 0u, 0u, 0u};
            qa1 = (uint4){0u, 0u, 0u, 0u};
        }
        uint4 qb0 = *(const uint4*)(bbase + 768 - bseg * 16 + bseg * 8);  // = Wt row + 768 + bseg*8

        __syncthreads();
        *(uint4*)&As[arow * 72 + aseg * 16 + 0] = qa0;
        *(uint4*)&As[arow * 72 + aseg * 16 + 8] = qa1;
        *(uint4*)&Bs[brow * 72 + bseg * 8] = qb0;
        __syncthreads();

        short8 af[2], bfr[4];
        #pragma unroll
        for (int mi = 0; mi < 2; mi++)
            af[mi] = *(const short8*)&As[(w * 32 + mi * 16 + fl) * 72 + quad * 8];
        #pragma unroll
        for (int ni = 0; ni < 4; ni++)
            bfr[ni] = *(const short8*)&Bs[(ni * 16 + fl) * 72 + quad * 8];
        #pragma unroll
        for (int mi = 0; mi < 2; mi++)
            #pragma unroll
            for (int ni = 0; ni < 4; ni++)
                acc[mi][ni] = __builtin_amdgcn_mfma_f32_16x16x32_bf16(af[mi], bfr[ni], acc[mi][ni], 0, 0, 0);
    }

    if (tr) {
        // R22 epilogue: stage bias+relu to LDS (reuses As/Bs region), then cooperative
        // float4 writes: 8/thread, 80B-contiguous runs in h1n[n][b][20].
        __syncthreads();
        float* ep = (float*)smem;              // [128][68]
        #pragma unroll
        for (int mi = 0; mi < 2; mi++) {
            #pragma unroll
            for (int ni = 0; ni < 4; ni++) {
                const int c = n0 + ni * 16 + fl;
                const float bias = b1f[c];     // b1f padded to 640
                #pragma unroll
                for (int r = 0; r < 4; r++)
                    ep[(w * 32 + mi * 16 + quad * 4 + r) * 68 + ni * 16 + fl]
                        = fmaxf(acc[mi][ni][r] + bias, 0.f);
            }
        }
        __syncthreads();
        #pragma unroll
        for (int s = 0; s < 8; s++) {
            const int i = s * 256 + tid;
            const int ml = i >> 4, cq = i & 15;
            const int c = n0 + cq * 4;
            const int m = m0 + ml;
            if (c < 600 && m < Btot) {
                const int cn = c / 20, ce = c - cn * 20;   // 20%4==0: chunk within net
                *(float4*)(h1 + ((size_t)cn * Btot + m) * 20 + ce)
                    = *(const float4*)&ep[ml * 68 + cq * 4];
            }
        }
    } else {
        #pragma unroll
        for (int mi = 0; mi < 2; mi++) {
            #pragma unroll
            for (int ni = 0; ni < 4; ni++) {
                const int c = n0 + ni * 16 + fl;
                #pragma unroll
                for (int r = 0; r < 4; r++) {
                    const int m = m0 + w * 32 + mi * 16 + quad * 4 + r;
                    if (c < 600 && m < Btot)
                        h1[(size_t)m * 600 + c] = fmaxf(acc[mi][ni][r] + b1f[c], 0.f);
                }
            }
        }
    }
}

// ---------------- K2w (main, validated R21): fused u-compute + priors MFMA, coalesced store ----------------
__global__ __launch_bounds__(256) void k2w(const float* __restrict__ h1n,
                                           const float* __restrict__ W2t,
                                           const float* __restrict__ b2f,
                                           const bfu* __restrict__ rwn,
                                           bfu* __restrict__ pri, int Btot) {
    __shared__ short us[128 * 40];
    __shared__ short pst[64 * 168];   // [row_local][160 + 8 pad]
    const int tid = threadIdx.x;
    const int n = blockIdx.y;
    const int b0 = blockIdx.x * 128;

    const int w = tid >> 6, lane = tid & 63;
    const int quad = lane >> 4, fl = lane & 15;
    short8 bfr[10];
    #pragma unroll
    for (int nj = 0; nj < 10; nj++)
        bfr[nj] = *(const short8*)(rwn + ((size_t)n * 160 + nj * 16 + fl) * 32 + quad * 8);

    {   // ---- phase 1: u for rows b0..b0+127 ----
        const int row = tid >> 1, half = tid & 1;
        int br = b0 + row; if (br >= Btot) br = Btot - 1;
        float h[20];
        const float* hp = h1n + ((size_t)n * Btot + br) * 20;
        #pragma unroll
        for (int d4 = 0; d4 < 20; d4 += 4) {
            float4 v = *(const float4*)(hp + d4);
            h[d4] = v.x; h[d4 + 1] = v.y; h[d4 + 2] = v.z; h[d4 + 3] = v.w;
        }
        const float* wn = W2t + n * 400;
        const float* bn = b2f + n * 20;
        float o[10], sq = 0.f;
        #pragma unroll
        for (int i = 0; i < 10; i++) {
            const int e = 2 * i + half;
            float acc = bn[e];
            #pragma unroll
            for (int d = 0; d < 20; d++) acc += h[d] * wn[e * 20 + d];
            acc = fmaxf(acc, 0.f);
            o[i] = acc;
            sq += acc * acc;
        }
        sq += __shfl_xor(sq, 1);
        float sc = (sq > 0.f) ? sqrtf(sq) / (1.f + sq) : 0.f;
        #pragma unroll
        for (int i = 0; i < 10; i++)
            us[row * 40 + 2 * i + half] = (short)f2bf(o[i] * sc);
        #pragma unroll
        for (int i = 10; i < 16; i++)
            us[row * 40 + 2 * i + half] = 0;
    }
    __syncthreads();

    // ---- phase 2: per-mi MFMA -> LDS stage -> coalesced write ----
    #pragma unroll
    for (int mi = 0; mi < 2; mi++) {
        short8 af = *(const short8*)&us[(w * 32 + mi * 16 + fl) * 40 + quad * 8];
        #pragma unroll
        for (int nj = 0; nj < 10; nj++) {
            floatx4 acc = (floatx4){0.f, 0.f, 0.f, 0.f};
            acc = __builtin_amdgcn_mfma_f32_16x16x32_bf16(af, bfr[nj], acc, 0, 0, 0);
            #pragma unroll
            for (int r = 0; r < 4; r++)
                pst[(w * 16 + quad * 4 + r) * 168 + nj * 16 + fl] = (short)f2bf(acc[r]);
        }
        __syncthreads();
        #pragma unroll
        for (int s = 0; s < 5; s++) {
            int i = s * 256 + tid;
            int rl = i / 20, seg = i - rl * 20;
            int row = b0 + (rl >> 4) * 32 + mi * 16 + (rl & 15);
            if (row < Btot)
                *(uint4*)(pri + (size_t)row * 4800 + n * 160 + seg * 8)
                    = *(const uint4*)&pst[rl * 168 + seg * 8];
        }
        __syncthreads();
    }
}

// ---------------- K2 core (fallback path, validated math) ----------------
__device__ __forceinline__ void k2_core(const float* hp, const float* wn, const float* bn,
                                        float* o, float& sc) {
    float h[20];
    #pragma unroll
    for (int d4 = 0; d4 < 20; d4 += 4) {
        float4 v = *(const float4*)(hp + d4);
        h[d4] = v.x; h[d4 + 1] = v.y; h[d4 + 2] = v.z; h[d4 + 3] = v.w;
    }
    float sq = 0.f;
    #pragma unroll
    for (int e = 0; e < 20; e++) {
        float acc = bn[e];
        #pragma unroll
        for (int d = 0; d < 20; d++) acc += h[d] * wn[d * 20 + e];
        acc = fmaxf(acc, 0.f);
        o[e] = acc;
        sq += acc * acc;
    }
    sc = (sq > 0.f) ? sqrtf(sq) / (1.f + sq) : 0.f;
}

// K2s (fallback, validated): u fp32 in place; flags written by prep_all block 0
__global__ __launch_bounds__(256) void k2s(const float* h1, const void* W2, const void* b2,
                                           float* u, const u32* flags, int total) {
    __shared__ float W2s[12000];
    __shared__ float b2s[600];
    const bool wb = flags[3] != 0, bb = flags[4] != 0;
    const int tid = threadIdx.x;
    for (int i = tid; i < 12000; i += 256) W2s[i] = ldf(W2, i, wb);
    for (int i = tid; i < 600; i += 256) b2s[i] = ldf(b2, i, bb);
    __syncthreads();

    int t = blockIdx.x * 256 + tid;
    if (t >= total) return;
    const int b = t / 30, n = t - b * 30;
    float o[20], sc;
    k2_core(h1 + (size_t)b * 600 + n * 20, &W2s[n * 400], &b2s[n * 20], o, sc);
    float* up = u + (size_t)b * 600 + n * 20;
    #pragma unroll
    for (int e4 = 0; e4 < 20; e4 += 4) {
        float4 v;
        v.x = o[e4] * sc; v.y = o[e4 + 1] * sc; v.z = o[e4 + 2] * sc; v.w = o[e4 + 3] * sc;
        *(float4*)(up + e4) = v;
    }
}

// ---------------- K3w: routing, LDS-broadcast allgather, n-major pri (validated R21) ----------------
__global__ __launch_bounds__(320, 4) void k3w(const bfu* __restrict__ pri_buf,
                                              float* __restrict__ out, int Btot) {
    __shared__ float L[2][300];
    __shared__ float P[2][300];
    __shared__ float S[2][200];   // [g][o*20 + k]
    const int tid = threadIdx.x;
    const int g = tid / 160, r = tid - g * 160;
    const int o = r >> 4, j = r & 15;
    const int b0 = blockIdx.x * 2;
    int bb = b0 + g; if (bb >= Btot) bb = Btot - 1;

    const int n0 = 2 * j, n1 = n0 + 1;
    float p0[16], p1[16];
    if (j < 15) {
        const bfu* pb = pri_buf + (size_t)bb * 4800 + n0 * 160 + o * 16;
        uint4 q0 = *(const uint4*)(pb);          // n0 k0..7
        uint4 q1 = *(const uint4*)(pb + 8);      // n0 k8..15
        uint4 q2 = *(const uint4*)(pb + 160);    // n1 k0..7
        uint4 q3 = *(const uint4*)(pb + 168);    // n1 k8..15
        unpack8(q0, p0); unpack8(q1, p0 + 8);
        unpack8(q2, p1); unpack8(q3, p1 + 8);
    } else {
        #pragma unroll
        for (int i = 0; i < 16; i++) { p0[i] = 0.f; p1[i] = 0.f; }
    }

    float L0 = 0.f, L1 = 0.f;
    float v = 0.f;
    #pragma unroll
    for (int it = 0; it < 3; it++) {
        float P0, P1;
        if (it == 0) {
            P0 = 0.1f; P1 = 0.1f;              // softmax(zeros) over 10 outputs
        } else {
            if (r < 30) {                       // dedicated softmax over o for net r
                float l[10];
                #pragma unroll
                for (int oo = 0; oo < 10; oo++) l[oo] = L[g][r * 10 + oo];
                float mx = l[0];
                #pragma unroll
                for (int oo = 1; oo < 10; oo++) mx = fmaxf(mx, l[oo]);
                float den = 0.f;
                #pragma unroll
                for (int oo = 0; oo < 10; oo++) { l[oo] = __expf(l[oo] - mx); den += l[oo]; }
                float inv = 1.f / den;
                #pragma unroll
                for (int oo = 0; oo < 10; oo++) P[g][r * 10 + oo] = l[oo] * inv;
            }
            __syncthreads();
            P0 = (j < 15) ? P[g][n0 * 10 + o] : 0.f;
            P1 = (j < 15) ? P[g][n1 * 10 + o] : 0.f;
        }

        float t[16];
        #pragma unroll
        for (int i = 0; i < 16; i++) t[i] = P0 * p0[i] + P1 * p1[i];

        // 16-lane transpose-reduce: lane j ends with s[k=j] (15 shuffles)
        #pragma unroll
        for (int i = 0; i < 8; i++) {
            float send = (j & 8) ? t[i] : t[i + 8];
            float recv = __shfl_xor(send, 8, 16);
            t[i] = ((j & 8) ? t[i + 8] : t[i]) + recv;
        }
        #pragma unroll
        for (int i = 0; i < 4; i++) {
            float send = (j & 4) ? t[i] : t[i + 4];
            float recv = __shfl_xor(send, 4, 16);
            t[i] = ((j & 4) ? t[i + 4] : t[i]) + recv;
        }
        #pragma unroll
        for (int i = 0; i < 2; i++) {
            float send = (j & 2) ? t[i] : t[i + 2];
            float recv = __shfl_xor(send, 2, 16);
            t[i] = ((j & 2) ? t[i + 2] : t[i]) + recv;
        }
        {
            float send = (j & 1) ? t[0] : t[1];
            float recv = __shfl_xor(send, 1, 16);
            t[0] = ((j & 1) ? t[1] : t[0]) + recv;
        }
        float s = t[0];                         // s[o, k=j]

        if (it < 2) {
            // wave-internal LDS allgather: write s, read back the o-group's 16 values
            S[g][o * 20 + j] = s;
            float4 s0 = *(const float4*)&S[g][o * 20 + 0];
            float4 s1 = *(const float4*)&S[g][o * 20 + 4];
            float4 s2 = *(const float4*)&S[g][o * 20 + 8];
            float4 s3 = *(const float4*)&S[g][o * 20 + 12];
            float sf[16];
            sf[0] = s0.x;  sf[1] = s0.y;  sf[2] = s0.z;  sf[3] = s0.w;
            sf[4] = s1.x;  sf[5] = s1.y;  sf[6] = s1.z;  sf[7] = s1.w;
            sf[8] = s2.x;  sf[9] = s2.y;  sf[10] = s2.z; sf[11] = s2.w;
            sf[12] = s3.x; sf[13] = s3.y; sf[14] = s3.z; sf[15] = s3.w;
            float q = 0.f;
            #pragma unroll
            for (int k = 0; k < 16; k++) q += sf[k] * sf[k];
            float scale = sqrtf(q) / (1.f + q);
            v = s * scale;
            float d0 = 0.f, d1 = 0.f;
            #pragma unroll
            for (int k = 0; k < 16; k++) {
                float vk = sf[k] * scale;
                d0 += p0[k] * vk;
                d1 += p1[k] * vk;
            }
            L0 += d0; L1 += d1;
            if (j < 15) {
                L[g][n0 * 10 + o] = L0;
                L[g][n1 * 10 + o] = L1;
            }
            __syncthreads();
        } else {
            float q = s * s;
            q += __shfl_xor(q, 1, 16);
            q += __shfl_xor(q, 2, 16);
            q += __shfl_xor(q, 4, 16);
            q += __shfl_xor(q, 8, 16);
            v = s * sqrtf(q) / (1.f + q);
        }
    }
    if ((b0 + g) < Btot) out[(size_t)(b0 + g) * 160 + r] = v;
}

// ---------------- K3y2 (fallback, validated @202us) ----------------
__global__ __launch_bounds__(640, 2) void k3y2(const float* __restrict__ u,
                                               const bfu* __restrict__ rwb,
                                               float* __restrict__ out, int Btot) {
    __shared__ float US[4][600];
    __shared__ float L[4][300];
    __shared__ float P[4][300];
    const int tid = threadIdx.x;
    const int g = tid / 160, r = tid - g * 160;
    const int o = r >> 4, k = r & 15;
    const int b0 = blockIdx.x * 4;

    {
        const int nf4 = 150;
        for (int i = tid; i < 4 * nf4; i += 640) {
            int gg = i / nf4, j = i - gg * nf4;
            int bb = b0 + gg; if (bb >= Btot) bb = Btot - 1;
            *(float4*)&US[gg][j * 4] = *(const float4*)(u + (size_t)bb * 600 + j * 4);
        }
        for (int i = tid; i < 1200; i += 640) L[i / 300][i % 300] = 0.f;
    }
    __syncthreads();

    float pri[30];
    const bfu* rp = rwb + o * 9600 + k * 20;
    #pragma unroll 2
    for (int n = 0; n < 30; n++) {
        const uint2* rq = (const uint2*)(rp + n * 320);
        float a = 0.f;
        #pragma unroll
        for (int jj = 0; jj < 5; jj++) {
            uint2 w = rq[jj];
            float4 uu = *(const float4*)&US[g][n * 20 + jj * 4];
            a += lo2f(w.x) * uu.x + hi2f(w.x) * uu.y + lo2f(w.y) * uu.z + hi2f(w.y) * uu.w;
        }
        pri[n] = a;
    }

    float v = 0.f;
    for (int it = 0; it < 3; it++) {
        if (r < 30) {
            const int n = r;
            float mx = L[g][n * 10];
            #pragma unroll
            for (int oo = 1; oo < 10; oo++) mx = fmaxf(mx, L[g][n * 10 + oo]);
            float e[10], den = 0.f;
            #pragma unroll
            for (int oo = 0; oo < 10; oo++) { e[oo] = __expf(L[g][n * 10 + oo] - mx); den += e[oo]; }
            float inv = 1.f / den;
            #pragma unroll
            for (int oo = 0; oo < 10; oo++) P[g][n * 10 + oo] = e[oo] * inv;
        }
        __syncthreads();
        float s = 0.f;
        #pragma unroll
        for (int n = 0; n < 30; n++) s += P[g][n * 10 + o] * pri[n];
        float q = s * s;
        q += __shfl_xor(q, 1, 16);
        q += __shfl_xor(q, 2, 16);
        q += __shfl_xor(q, 4, 16);
        q += __shfl_xor(q, 8, 16);
        v = s * sqrtf(q) / (1.f + q);
        if (it < 2) {
            #pragma unroll 5
            for (int n = 0; n < 30; n++) {
                float t = pri[n] * v;
                t += __shfl_xor(t, 1, 16);
                t += __shfl_xor(t, 2, 16);
                t += __shfl_xor(t, 4, 16);
                t += __shfl_xor(t, 8, 16);
                if (k == 0) L[g][n * 10 + o] += t;
            }
            __syncthreads();
        }
    }
    if ((b0 + g) < Btot) out[(size_t)(b0 + g) * 160 + r] = v;
}

extern "C" void kernel_launch(void* const* d_in, const int* in_sizes, int n_in,
                              void* d_out, int out_size, void* d_ws, size_t ws_size,
                              hipStream_t stream) {
    // ---- size-based input matching (validated) ----
    int ix = -1, iw1 = -1, ib1 = -1, iw2 = -1, ib2 = -1, irw = -1;
    for (int i = 0; i < n_in; i++) {
        int s = in_sizes[i];
        if (s == 470400 && iw1 < 0) iw1 = i;
        else if (s == 12000 && iw2 < 0) iw2 = i;
        else if (s == 96000 && irw < 0) irw = i;
        else if (s == 600) { if (ib1 < 0) ib1 = i; else if (ib2 < 0) ib2 = i; }
    }
    long bestsz = -1;
    for (int i = 0; i < n_in; i++) {
        if (i == iw1 || i == iw2 || i == irw || i == ib1 || i == ib2) continue;
        if ((long)in_sizes[i] > bestsz) { bestsz = in_sizes[i]; ix = i; }
    }
    if (ix < 0 || iw1 < 0 || ib1 < 0 || iw2 < 0 || ib2 < 0 || irw < 0) {
        ix = 0; iw1 = 1; ib1 = 2; iw2 = 3; ib2 = 4; irw = 5;
    }
    const void* x  = d_in[ix];
    const void* W1 = d_in[iw1];
    const void* b1 = d_in[ib1];
    const void* W2 = d_in[iw2];
    const void* b2 = d_in[ib2];
    const void* rw = d_in[irw];
    const int B = in_sizes[ix] / 784;
    float* out = (float*)d_out;

    // ---- ws layout (byte offsets, all 16B-aligned) ----
    char* base = (char*)d_ws;
    size_t off = 0;
    float* h1u  = (float*)(base + off); off += (size_t)B * 2400;       // B*600 f32
    float* b1f  = (float*)(base + off); off += 2560;                   // 640 f32
    u32*  flags = (u32*)(base + off);   off += 32;                     // 8 u32
    bfu*   Wt   = (bfu*)(base + off);   off += 1024000;                // 640*800 bf16
    bfu*   rwb  = (bfu*)(base + off);   off += 192000;                 // 96000 bf16 (fallback)
    size_t fb_bytes = off;
    bfu*   rwn  = (bfu*)(base + off);   off += 307200;                 // 30*160*32 bf16
    float* W2t  = (float*)(base + off); off += 48000;                  // 30*20*20 f32
    float* b2f  = (float*)(base + off); off += 2560;                   // 640 f32
    bfu*   pri  = (bfu*)(base + off);   off += (size_t)B * 9600;       // B*4800 bf16
    size_t main_bytes = off;

    const int mode = (ws_size >= main_bytes) ? 0 : 1;   // fixed per-call -> graph-safe
    const int prep_total = 128000 + 640 + (mode == 0 ? (153600 + 12000 + 640) : 96000);

    prep_all<<<(prep_total + 255) / 256, 256, 0, stream>>>(x, W1, b1, W2, b2, rw,
                                                           Wt, b1f, rwb, rwn,
                                                           W2t, b2f, flags, mode);
    k1m<<<dim3((B + 127) / 128, 10), 256, 0, stream>>>(x, Wt, b1f, flags, h1u, B,
                                                       mode == 0 ? 1 : 0);
    if (mode == 0) {
        k2w<<<dim3((B + 127) / 128, 30), 256, 0, stream>>>(h1u, W2t, b2f, rwn, pri, B);
        k3w<<<(B + 1) / 2, 320, 0, stream>>>(pri, out, B);
    } else {
        (void)fb_bytes;
        k2s<<<(B * 30 + 255) / 256, 256, 0, stream>>>(h1u, W2, b2, h1u, flags, B * 30);
        k3y2<<<(B + 3) / 4, 640, 0, stream>>>(h1u, rwb, out, B);
    }
}

// Round 10
// 166.076 us; speedup vs baseline: 1.0424x; 1.0424x over previous
//
#include <hip/hip_runtime.h>

// B(derived), IN_DIM=784, NUM_NETS=30, N_NODES=20, NUM_OUT=10, DIM_OUT=16, NUM_ITER=3
// Validated: size-based binding; k2w fused u+priors MFMA w/ coalesced n-major pri store;
// k3w routing w/ LDS-broadcast allgather; prep self-detect (flags->ws, no detect launch).
// R24: (a) REVERT R23's x-direct read (regressed +10us: 2x staging bytes + fp32 decode
// on a latency-bound kernel with only 2.5 blocks/CU). xb bf16 staging restored in prep
// (R20-validated 4-wide code). (b) k1m -> k1n: BM 128->64, 128-thread blocks (2 waves).
// Grid 640->1280 blocks (5/CU), LDS 18.4KB -> up to 8 blocks/CU = 16 waves: doubles TLP
// on the latency-bound GEMM at identical per-wave MFMA work (wave tile still 32x64).
// Epilogue: ep[64][68] f32 staged, 8 coalesced float4 stores/thread (R22 recipe).
// Fallback k2s+k3y2 unchanged.

typedef unsigned short bfu;
typedef unsigned int u32;
typedef __attribute__((ext_vector_type(8))) short short8;
typedef __attribute__((ext_vector_type(4))) float floatx4;

__device__ __forceinline__ float bf2f(bfu u) { union { u32 i; float f; } v; v.i = ((u32)u) << 16; return v.f; }
__device__ __forceinline__ float lo2f(u32 w) { union { u32 i; float f; } v; v.i = w << 16; return v.f; }
__device__ __forceinline__ float hi2f(u32 w) { union { u32 i; float f; } v; v.i = w & 0xffff0000u; return v.f; }
__device__ __forceinline__ float ldf(const void* p, int idx, bool b16) {
    return b16 ? bf2f(((const bfu*)p)[idx]) : ((const float*)p)[idx];
}
__device__ __forceinline__ bfu f2bf(float f) {   // RNE
    u32 u = __float_as_uint(f);
    return (bfu)((u + 0x7FFFu + ((u >> 16) & 1u)) >> 16);
}
__device__ __forceinline__ void unpack8(uint4 q, float* dst) {
    dst[0] = lo2f(q.x); dst[1] = hi2f(q.x);
    dst[2] = lo2f(q.y); dst[3] = hi2f(q.y);
    dst[4] = lo2f(q.z); dst[5] = hi2f(q.z);
    dst[6] = lo2f(q.w); dst[7] = hi2f(q.w);
}
__device__ __forceinline__ u32 detect_one(const u32* p) {
    int c = 0;
    for (int i = 0; i < 64; i++) {
        u32 e = (p[i] >> 7) & 0xFF;
        c += (e >= 64 && e <= 140) ? 1 : 0;
    }
    return (c >= 48) ? 1u : 0u;
}

// ---- prep_all (R24): xb4 | Wt4 | b1f | (rwn|W2t|b2f if mode==0 else rwb);
//      self-detecting; block 0 publishes flags (fallback k2s). ----
__global__ void prep_all(const void* x, const void* W1, const void* b1,
                         const void* W2, const void* b2, const void* rw,
                         bfu* __restrict__ xb, bfu* __restrict__ Wt,
                         float* __restrict__ b1f, bfu* __restrict__ rwb,
                         bfu* __restrict__ rwn, float* __restrict__ W2t,
                         float* __restrict__ b2f,
                         u32* __restrict__ flags_g, int B, int mode) {
    __shared__ u32 flg[6];
    {
        const int t = threadIdx.x;
        if (t < 6) {
            const u32* p = (t == 0) ? (const u32*)x : (t == 1) ? (const u32*)W1
                         : (t == 2) ? (const u32*)b1 : (t == 3) ? (const u32*)W2
                         : (t == 4) ? (const u32*)b2 : (const u32*)rw;
            flg[t] = detect_one(p);
        }
    }
    __syncthreads();
    if (blockIdx.x == 0 && threadIdx.x < 6) flags_g[threadIdx.x] = flg[threadIdx.x];

    const int idx = blockIdx.x * 256 + threadIdx.x;
    const int nxb4 = B * 200;
    if (idx < nxb4) {                                  // xb[B][800] bf16, 4/thread
        const bool b16 = flg[0] != 0;
        int b = idx / 200, kk = (idx - b * 200) * 4;
        ushort4 w;
        if (kk < 784) {                                // 784%4==0: chunks never straddle
            int src = b * 784 + kk;
            if (b16) {
                w = *(const ushort4*)((const bfu*)x + src);
            } else {
                float4 f = *(const float4*)((const float*)x + src);
                w.x = f2bf(f.x); w.y = f2bf(f.y); w.z = f2bf(f.z); w.w = f2bf(f.w);
            }
        } else { w.x = 0; w.y = 0; w.z = 0; w.w = 0; }
        *(ushort4*)(xb + b * 800 + kk) = w;
        return;
    }
    int i2 = idx - nxb4;
    if (i2 < 128000) {                                 // Wt[c][k] bf16, 4/thread
        const bool wb = flg[1] != 0;
        int c = i2 / 200, k = (i2 - c * 200) * 4;
        ushort4 w; w.x = 0; w.y = 0; w.z = 0; w.w = 0;
        if (c < 600 && k < 784) {
            int nn = c / 20, o = c - nn * 20;
            int src = nn * 15680 + k * 20 + o;         // k-stride 20
            if (wb) {
                const bfu* p = (const bfu*)W1;
                w.x = p[src]; w.y = p[src + 20]; w.z = p[src + 40]; w.w = p[src + 60];
            } else {
                const float* p = (const float*)W1;
                w.x = f2bf(p[src]); w.y = f2bf(p[src + 20]);
                w.z = f2bf(p[src + 40]); w.w = f2bf(p[src + 60]);
            }
        }
        *(ushort4*)(Wt + c * 800 + k) = w;
        return;
    }
    i2 -= 128000;
    if (i2 < 640) {                                    // b1f fp32
        b1f[i2] = (i2 < 600) ? ldf(b1, i2, flg[2] != 0) : 0.f;
        return;
    }
    i2 -= 640;
    if (mode == 0) {
        if (i2 < 153600) {                             // rwn[n][col=o*16+k][dd<32] bf16, K-pad
            const bool rb = flg[5] != 0;
            int dd = i2 % 32;
            int col = (i2 / 32) % 160;
            int n = i2 / 5120;
            bfu v = 0;
            if (dd < 20) {
                int o = col / 16, kk = col % 16;
                int src = o * 9600 + n * 320 + dd * 16 + kk;
                v = rb ? ((const bfu*)rw)[src] : f2bf(((const float*)rw)[src]);
            }
            rwn[i2] = v;
            return;
        }
        i2 -= 153600;
        if (i2 < 12000) {                              // W2t[n][e][d] fp32 = W2[n][d][e]
            int d = i2 % 20;
            int e = (i2 / 20) % 20;
            int n = i2 / 400;
            W2t[i2] = ldf(W2, n * 400 + d * 20 + e, flg[3] != 0);
            return;
        }
        i2 -= 12000;
        if (i2 < 640) {                                // b2f fp32
            b2f[i2] = (i2 < 600) ? ldf(b2, i2, flg[4] != 0) : 0.f;
        }
    } else {
        if (i2 < 96000) {                              // rwb[o][n][k][d] bf16 (fallback k3y2)
            const bool rb = flg[5] != 0;
            int d = i2 % 20;
            int k = (i2 / 20) % 16;
            int n = (i2 / 320) % 30;
            int o = i2 / 9600;
            int src = o * 9600 + n * 320 + d * 16 + k;
            rwb[i2] = rb ? ((const bfu*)rw)[src] : f2bf(((const float*)rw)[src]);
        }
    }
}

// ---------------- K1n (R24): h1 = relu(xb @ Wt^T + b1), BM=64, 128 threads ----------------
// Grid (ceil(B/64), 10); 2 waves; wave w owns rows w*32..+31 (tile 32x64), same MFMA
// mapping as validated k1m. tr==1: h1 [n][b][20] via LDS-staged coalesced stores.
__global__ __launch_bounds__(128, 4) void k1n(const bfu* __restrict__ xb, const bfu* __restrict__ Wt,
                                              const float* __restrict__ b1f,
                                              float* __restrict__ h1, int Btot, int tr) {
    __shared__ __align__(16) char smem[64 * 72 * 2 * 2];   // As[64][72]+Bs[64][72]=18432B >= ep 17408B
    short* As = (short*)smem;                   // [64][72]
    short* Bs = (short*)(smem + 64 * 72 * 2);   // [64][72]
    const int tid = threadIdx.x;
    const int w = tid >> 6, lane = tid & 63;
    const int quad = lane >> 4, fl = lane & 15;
    const int m0 = blockIdx.x * 64, n0 = blockIdx.y * 64;

    floatx4 acc[2][4];
    #pragma unroll
    for (int mi = 0; mi < 2; mi++)
        #pragma unroll
        for (int ni = 0; ni < 4; ni++) acc[mi][ni] = (floatx4){0.f, 0.f, 0.f, 0.f};

    const int arow = tid >> 1, aseg = tid & 1;    // 2 thr/row, 64B each (A and B alike)
    int agrow = m0 + arow; if (agrow >= Btot) agrow = Btot - 1;
    const bfu* abase = xb + (size_t)agrow * 800 + aseg * 32;
    const bfu* bbase = Wt + (size_t)(n0 + arow) * 800 + aseg * 32;

    // 12 steps of BK=64
    for (int k0 = 0; k0 < 768; k0 += 64) {
        uint4 qa0 = *(const uint4*)(abase + k0);
        uint4 qa1 = *(const uint4*)(abase + k0 + 8);
        uint4 qa2 = *(const uint4*)(abase + k0 + 16);
        uint4 qa3 = *(const uint4*)(abase + k0 + 24);
        uint4 qb0 = *(const uint4*)(bbase + k0);
        uint4 qb1 = *(const uint4*)(bbase + k0 + 8);
        uint4 qb2 = *(const uint4*)(bbase + k0 + 16);
        uint4 qb3 = *(const uint4*)(bbase + k0 + 24);

        __syncthreads();
        *(uint4*)&As[arow * 72 + aseg * 32 + 0]  = qa0;
        *(uint4*)&As[arow * 72 + aseg * 32 + 8]  = qa1;
        *(uint4*)&As[arow * 72 + aseg * 32 + 16] = qa2;
        *(uint4*)&As[arow * 72 + aseg * 32 + 24] = qa3;
        *(uint4*)&Bs[arow * 72 + aseg * 32 + 0]  = qb0;
        *(uint4*)&Bs[arow * 72 + aseg * 32 + 8]  = qb1;
        *(uint4*)&Bs[arow * 72 + aseg * 32 + 16] = qb2;
        *(uint4*)&Bs[arow * 72 + aseg * 32 + 24] = qb3;
        __syncthreads();

        short8 af[2][2], bfr[4][2];
        #pragma unroll
        for (int mi = 0; mi < 2; mi++)
            #pragma unroll
            for (int kk = 0; kk < 2; kk++)
                af[mi][kk] = *(const short8*)&As[(w * 32 + mi * 16 + fl) * 72 + kk * 32 + quad * 8];
        #pragma unroll
        for (int ni = 0; ni < 4; ni++)
            #pragma unroll
            for (int kk = 0; kk < 2; kk++)
                bfr[ni][kk] = *(const short8*)&Bs[(ni * 16 + fl) * 72 + kk * 32 + quad * 8];
        #pragma unroll
        for (int kk = 0; kk < 2; kk++)
            #pragma unroll
            for (int mi = 0; mi < 2; mi++)
                #pragma unroll
                for (int ni = 0; ni < 4; ni++)
                    acc[mi][ni] = __builtin_amdgcn_mfma_f32_16x16x32_bf16(af[mi][kk], bfr[ni][kk], acc[mi][ni], 0, 0, 0);
    }

    // tail step: k0=768, 32 wide (xb/Wt rows are 800 wide, 784..799 = zero pad)
    {
        const bfu* at = xb + (size_t)agrow * 800 + 768 + aseg * 16;
        const bfu* bt = Wt + (size_t)(n0 + arow) * 800 + 768 + aseg * 16;
        uint4 qa0 = *(const uint4*)(at);
        uint4 qa1 = *(const uint4*)(at + 8);
        uint4 qb0 = *(const uint4*)(bt);
        uint4 qb1 = *(const uint4*)(bt + 8);

        __syncthreads();
        *(uint4*)&As[arow * 72 + aseg * 16 + 0] = qa0;
        *(uint4*)&As[arow * 72 + aseg * 16 + 8] = qa1;
        *(uint4*)&Bs[arow * 72 + aseg * 16 + 0] = qb0;
        *(uint4*)&Bs[arow * 72 + aseg * 16 + 8] = qb1;
        __syncthreads();

        short8 af[2], bfr[4];
        #pragma unroll
        for (int mi = 0; mi < 2; mi++)
            af[mi] = *(const short8*)&As[(w * 32 + mi * 16 + fl) * 72 + quad * 8];
        #pragma unroll
        for (int ni = 0; ni < 4; ni++)
            bfr[ni] = *(const short8*)&Bs[(ni * 16 + fl) * 72 + quad * 8];
        #pragma unroll
        for (int mi = 0; mi < 2; mi++)
            #pragma unroll
            for (int ni = 0; ni < 4; ni++)
                acc[mi][ni] = __builtin_amdgcn_mfma_f32_16x16x32_bf16(af[mi], bfr[ni], acc[mi][ni], 0, 0, 0);
    }

    if (tr) {
        // stage bias+relu to LDS (reuses As/Bs region), then cooperative float4 writes
        __syncthreads();
        float* ep = (float*)smem;              // [64][68] = 17408B
        #pragma unroll
        for (int mi = 0; mi < 2; mi++) {
            #pragma unroll
            for (int ni = 0; ni < 4; ni++) {
                const int c = n0 + ni * 16 + fl;
                const float bias = b1f[c];     // b1f padded to 640
                #pragma unroll
                for (int r = 0; r < 4; r++)
                    ep[(w * 32 + mi * 16 + quad * 4 + r) * 68 + ni * 16 + fl]
                        = fmaxf(acc[mi][ni][r] + bias, 0.f);
            }
        }
        __syncthreads();
        #pragma unroll
        for (int s = 0; s < 8; s++) {
            const int i = s * 128 + tid;       // 1024 float4 total
            const int ml = i >> 4, cq = i & 15;
            const int c = n0 + cq * 4;
            const int m = m0 + ml;
            if (c < 600 && m < Btot) {
                const int cn = c / 20, ce = c - cn * 20;   // 20%4==0: chunk within net
                *(float4*)(h1 + ((size_t)cn * Btot + m) * 20 + ce)
                    = *(const float4*)&ep[ml * 68 + cq * 4];
            }
        }
    } else {
        #pragma unroll
        for (int mi = 0; mi < 2; mi++) {
            #pragma unroll
            for (int ni = 0; ni < 4; ni++) {
                const int c = n0 + ni * 16 + fl;
                #pragma unroll
                for (int r = 0; r < 4; r++) {
                    const int m = m0 + w * 32 + mi * 16 + quad * 4 + r;
                    if (c < 600 && m < Btot)
                        h1[(size_t)m * 600 + c] = fmaxf(acc[mi][ni][r] + b1f[c], 0.f);
                }
            }
        }
    }
}

// ---------------- K2w (main, validated R21): fused u-compute + priors MFMA, coalesced store ----------------
__global__ __launch_bounds__(256) void k2w(const float* __restrict__ h1n,
                                           const float* __restrict__ W2t,
                                           const float* __restrict__ b2f,
                                           const bfu* __restrict__ rwn,
                                           bfu* __restrict__ pri, int Btot) {
    __shared__ short us[128 * 40];
    __shared__ short pst[64 * 168];   // [row_local][160 + 8 pad]
    const int tid = threadIdx.x;
    const int n = blockIdx.y;
    const int b0 = blockIdx.x * 128;

    const int w = tid >> 6, lane = tid & 63;
    const int quad = lane >> 4, fl = lane & 15;
    short8 bfr[10];
    #pragma unroll
    for (int nj = 0; nj < 10; nj++)
        bfr[nj] = *(const short8*)(rwn + ((size_t)n * 160 + nj * 16 + fl) * 32 + quad * 8);

    {   // ---- phase 1: u for rows b0..b0+127 ----
        const int row = tid >> 1, half = tid & 1;
        int br = b0 + row; if (br >= Btot) br = Btot - 1;
        float h[20];
        const float* hp = h1n + ((size_t)n * Btot + br) * 20;
        #pragma unroll
        for (int d4 = 0; d4 < 20; d4 += 4) {
            float4 v = *(const float4*)(hp + d4);
            h[d4] = v.x; h[d4 + 1] = v.y; h[d4 + 2] = v.z; h[d4 + 3] = v.w;
        }
        const float* wn = W2t + n * 400;
        const float* bn = b2f + n * 20;
        float o[10], sq = 0.f;
        #pragma unroll
        for (int i = 0; i < 10; i++) {
            const int e = 2 * i + half;
            float acc = bn[e];
            #pragma unroll
            for (int d = 0; d < 20; d++) acc += h[d] * wn[e * 20 + d];
            acc = fmaxf(acc, 0.f);
            o[i] = acc;
            sq += acc * acc;
        }
        sq += __shfl_xor(sq, 1);
        float sc = (sq > 0.f) ? sqrtf(sq) / (1.f + sq) : 0.f;
        #pragma unroll
        for (int i = 0; i < 10; i++)
            us[row * 40 + 2 * i + half] = (short)f2bf(o[i] * sc);
        #pragma unroll
        for (int i = 10; i < 16; i++)
            us[row * 40 + 2 * i + half] = 0;
    }
    __syncthreads();

    // ---- phase 2: per-mi MFMA -> LDS stage -> coalesced write ----
    #pragma unroll
    for (int mi = 0; mi < 2; mi++) {
        short8 af = *(const short8*)&us[(w * 32 + mi * 16 + fl) * 40 + quad * 8];
        #pragma unroll
        for (int nj = 0; nj < 10; nj++) {
            floatx4 acc = (floatx4){0.f, 0.f, 0.f, 0.f};
            acc = __builtin_amdgcn_mfma_f32_16x16x32_bf16(af, bfr[nj], acc, 0, 0, 0);
            #pragma unroll
            for (int r = 0; r < 4; r++)
                pst[(w * 16 + quad * 4 + r) * 168 + nj * 16 + fl] = (short)f2bf(acc[r]);
        }
        __syncthreads();
        #pragma unroll
        for (int s = 0; s < 5; s++) {
            int i = s * 256 + tid;
            int rl = i / 20, seg = i - rl * 20;
            int row = b0 + (rl >> 4) * 32 + mi * 16 + (rl & 15);
            if (row < Btot)
                *(uint4*)(pri + (size_t)row * 4800 + n * 160 + seg * 8)
                    = *(const uint4*)&pst[rl * 168 + seg * 8];
        }
        __syncthreads();
    }
}

// ---------------- K2 core (fallback path, validated math) ----------------
__device__ __forceinline__ void k2_core(const float* hp, const float* wn, const float* bn,
                                        float* o, float& sc) {
    float h[20];
    #pragma unroll
    for (int d4 = 0; d4 < 20; d4 += 4) {
        float4 v = *(const float4*)(hp + d4);
        h[d4] = v.x; h[d4 + 1] = v.y; h[d4 + 2] = v.z; h[d4 + 3] = v.w;
    }
    float sq = 0.f;
    #pragma unroll
    for (int e = 0; e < 20; e++) {
        float acc = bn[e];
        #pragma unroll
        for (int d = 0; d < 20; d++) acc += h[d] * wn[d * 20 + e];
        acc = fmaxf(acc, 0.f);
        o[e] = acc;
        sq += acc * acc;
    }
    sc = (sq > 0.f) ? sqrtf(sq) / (1.f + sq) : 0.f;
}

// K2s (fallback, validated): u fp32 in place; flags written by prep_all block 0
__global__ __launch_bounds__(256) void k2s(const float* h1, const void* W2, const void* b2,
                                           float* u, const u32* flags, int total) {
    __shared__ float W2s[12000];
    __shared__ float b2s[600];
    const bool wb = flags[3] != 0, bb = flags[4] != 0;
    const int tid = threadIdx.x;
    for (int i = tid; i < 12000; i += 256) W2s[i] = ldf(W2, i, wb);
    for (int i = tid; i < 600; i += 256) b2s[i] = ldf(b2, i, bb);
    __syncthreads();

    int t = blockIdx.x * 256 + tid;
    if (t >= total) return;
    const int b = t / 30, n = t - b * 30;
    float o[20], sc;
    k2_core(h1 + (size_t)b * 600 + n * 20, &W2s[n * 400], &b2s[n * 20], o, sc);
    float* up = u + (size_t)b * 600 + n * 20;
    #pragma unroll
    for (int e4 = 0; e4 < 20; e4 += 4) {
        float4 v;
        v.x = o[e4] * sc; v.y = o[e4 + 1] * sc; v.z = o[e4 + 2] * sc; v.w = o[e4 + 3] * sc;
        *(float4*)(up + e4) = v;
    }
}

// ---------------- K3w: routing, LDS-broadcast allgather, n-major pri (validated R21) ----------------
__global__ __launch_bounds__(320, 4) void k3w(const bfu* __restrict__ pri_buf,
                                              float* __restrict__ out, int Btot) {
    __shared__ float L[2][300];
    __shared__ float P[2][300];
    __shared__ float S[2][200];   // [g][o*20 + k]
    const int tid = threadIdx.x;
    const int g = tid / 160, r = tid - g * 160;
    const int o = r >> 4, j = r & 15;
    const int b0 = blockIdx.x * 2;
    int bb = b0 + g; if (bb >= Btot) bb = Btot - 1;

    const int n0 = 2 * j, n1 = n0 + 1;
    float p0[16], p1[16];
    if (j < 15) {
        const bfu* pb = pri_buf + (size_t)bb * 4800 + n0 * 160 + o * 16;
        uint4 q0 = *(const uint4*)(pb);          // n0 k0..7
        uint4 q1 = *(const uint4*)(pb + 8);      // n0 k8..15
        uint4 q2 = *(const uint4*)(pb + 160);    // n1 k0..7
        uint4 q3 = *(const uint4*)(pb + 168);    // n1 k8..15
        unpack8(q0, p0); unpack8(q1, p0 + 8);
        unpack8(q2, p1); unpack8(q3, p1 + 8);
    } else {
        #pragma unroll
        for (int i = 0; i < 16; i++) { p0[i] = 0.f; p1[i] = 0.f; }
    }

    float L0 = 0.f, L1 = 0.f;
    float v = 0.f;
    #pragma unroll
    for (int it = 0; it < 3; it++) {
        float P0, P1;
        if (it == 0) {
            P0 = 0.1f; P1 = 0.1f;              // softmax(zeros) over 10 outputs
        } else {
            if (r < 30) {                       // dedicated softmax over o for net r
                float l[10];
                #pragma unroll
                for (int oo = 0; oo < 10; oo++) l[oo] = L[g][r * 10 + oo];
                float mx = l[0];
                #pragma unroll
                for (int oo = 1; oo < 10; oo++) mx = fmaxf(mx, l[oo]);
                float den = 0.f;
                #pragma unroll
                for (int oo = 0; oo < 10; oo++) { l[oo] = __expf(l[oo] - mx); den += l[oo]; }
                float inv = 1.f / den;
                #pragma unroll
                for (int oo = 0; oo < 10; oo++) P[g][r * 10 + oo] = l[oo] * inv;
            }
            __syncthreads();
            P0 = (j < 15) ? P[g][n0 * 10 + o] : 0.f;
            P1 = (j < 15) ? P[g][n1 * 10 + o] : 0.f;
        }

        float t[16];
        #pragma unroll
        for (int i = 0; i < 16; i++) t[i] = P0 * p0[i] + P1 * p1[i];

        // 16-lane transpose-reduce: lane j ends with s[k=j] (15 shuffles)
        #pragma unroll
        for (int i = 0; i < 8; i++) {
            float send = (j & 8) ? t[i] : t[i + 8];
            float recv = __shfl_xor(send, 8, 16);
            t[i] = ((j & 8) ? t[i + 8] : t[i]) + recv;
        }
        #pragma unroll
        for (int i = 0; i < 4; i++) {
            float send = (j & 4) ? t[i] : t[i + 4];
            float recv = __shfl_xor(send, 4, 16);
            t[i] = ((j & 4) ? t[i + 4] : t[i]) + recv;
        }
        #pragma unroll
        for (int i = 0; i < 2; i++) {
            float send = (j & 2) ? t[i] : t[i + 2];
            float recv = __shfl_xor(send, 2, 16);
            t[i] = ((j & 2) ? t[i + 2] : t[i]) + recv;
        }
        {
            float send = (j & 1) ? t[0] : t[1];
            float recv = __shfl_xor(send, 1, 16);
            t[0] = ((j & 1) ? t[1] : t[0]) + recv;
        }
        float s = t[0];                         // s[o, k=j]

        if (it < 2) {
            // wave-internal LDS allgather: write s, read back the o-group's 16 values
            S[g][o * 20 + j] = s;
            float4 s0 = *(const float4*)&S[g][o * 20 + 0];
            float4 s1 = *(const float4*)&S[g][o * 20 + 4];
            float4 s2 = *(const float4*)&S[g][o * 20 + 8];
            float4 s3 = *(const float4*)&S[g][o * 20 + 12];
            float sf[16];
            sf[0] = s0.x;  sf[1] = s0.y;  sf[2] = s0.z;  sf[3] = s0.w;
            sf[4] = s1.x;  sf[5] = s1.y;  sf[6] = s1.z;  sf[7] = s1.w;
            sf[8] = s2.x;  sf[9] = s2.y;  sf[10] = s2.z; sf[11] = s2.w;
            sf[12] = s3.x; sf[13] = s3.y; sf[14] = s3.z; sf[15] = s3.w;
            float q = 0.f;
            #pragma unroll
            for (int k = 0; k < 16; k++) q += sf[k] * sf[k];
            float scale = sqrtf(q) / (1.f + q);
            v = s * scale;
            float d0 = 0.f, d1 = 0.f;
            #pragma unroll
            for (int k = 0; k < 16; k++) {
                float vk = sf[k] * scale;
                d0 += p0[k] * vk;
                d1 += p1[k] * vk;
            }
            L0 += d0; L1 += d1;
            if (j < 15) {
                L[g][n0 * 10 + o] = L0;
                L[g][n1 * 10 + o] = L1;
            }
            __syncthreads();
        } else {
            float q = s * s;
            q += __shfl_xor(q, 1, 16);
            q += __shfl_xor(q, 2, 16);
            q += __shfl_xor(q, 4, 16);
            q += __shfl_xor(q, 8, 16);
            v = s * sqrtf(q) / (1.f + q);
        }
    }
    if ((b0 + g) < Btot) out[(size_t)(b0 + g) * 160 + r] = v;
}

// ---------------- K3y2 (fallback, validated @202us) ----------------
__global__ __launch_bounds__(640, 2) void k3y2(const float* __restrict__ u,
                                               const bfu* __restrict__ rwb,
                                               float* __restrict__ out, int Btot) {
    __shared__ float US[4][600];
    __shared__ float L[4][300];
    __shared__ float P[4][300];
    const int tid = threadIdx.x;
    const int g = tid / 160, r = tid - g * 160;
    const int o = r >> 4, k = r & 15;
    const int b0 = blockIdx.x * 4;

    {
        const int nf4 = 150;
        for (int i = tid; i < 4 * nf4; i += 640) {
            int gg = i / nf4, j = i - gg * nf4;
            int bb = b0 + gg; if (bb >= Btot) bb = Btot - 1;
            *(float4*)&US[gg][j * 4] = *(const float4*)(u + (size_t)bb * 600 + j * 4);
        }
        for (int i = tid; i < 1200; i += 640) L[i / 300][i % 300] = 0.f;
    }
    __syncthreads();

    float pri[30];
    const bfu* rp = rwb + o * 9600 + k * 20;
    #pragma unroll 2
    for (int n = 0; n < 30; n++) {
        const uint2* rq = (const uint2*)(rp + n * 320);
        float a = 0.f;
        #pragma unroll
        for (int jj = 0; jj < 5; jj++) {
            uint2 w = rq[jj];
            float4 uu = *(const float4*)&US[g][n * 20 + jj * 4];
            a += lo2f(w.x) * uu.x + hi2f(w.x) * uu.y + lo2f(w.y) * uu.z + hi2f(w.y) * uu.w;
        }
        pri[n] = a;
    }

    float v = 0.f;
    for (int it = 0; it < 3; it++) {
        if (r < 30) {
            const int n = r;
            float mx = L[g][n * 10];
            #pragma unroll
            for (int oo = 1; oo < 10; oo++) mx = fmaxf(mx, L[g][n * 10 + oo]);
            float e[10], den = 0.f;
            #pragma unroll
            for (int oo = 0; oo < 10; oo++) { e[oo] = __expf(L[g][n * 10 + oo] - mx); den += e[oo]; }
            float inv = 1.f / den;
            #pragma unroll
            for (int oo = 0; oo < 10; oo++) P[g][n * 10 + oo] = e[oo] * inv;
        }
        __syncthreads();
        float s = 0.f;
        #pragma unroll
        for (int n = 0; n < 30; n++) s += P[g][n * 10 + o] * pri[n];
        float q = s * s;
        q += __shfl_xor(q, 1, 16);
        q += __shfl_xor(q, 2, 16);
        q += __shfl_xor(q, 4, 16);
        q += __shfl_xor(q, 8, 16);
        v = s * sqrtf(q) / (1.f + q);
        if (it < 2) {
            #pragma unroll 5
            for (int n = 0; n < 30; n++) {
                float t = pri[n] * v;
                t += __shfl_xor(t, 1, 16);
                t += __shfl_xor(t, 2, 16);
                t += __shfl_xor(t, 4, 16);
                t += __shfl_xor(t, 8, 16);
                if (k == 0) L[g][n * 10 + o] += t;
            }
            __syncthreads();
        }
    }
    if ((b0 + g) < Btot) out[(size_t)(b0 + g) * 160 + r] = v;
}

extern "C" void kernel_launch(void* const* d_in, const int* in_sizes, int n_in,
                              void* d_out, int out_size, void* d_ws, size_t ws_size,
                              hipStream_t stream) {
    // ---- size-based input matching (validated) ----
    int ix = -1, iw1 = -1, ib1 = -1, iw2 = -1, ib2 = -1, irw = -1;
    for (int i = 0; i < n_in; i++) {
        int s = in_sizes[i];
        if (s == 470400 && iw1 < 0) iw1 = i;
        else if (s == 12000 && iw2 < 0) iw2 = i;
        else if (s == 96000 && irw < 0) irw = i;
        else if (s == 600) { if (ib1 < 0) ib1 = i; else if (ib2 < 0) ib2 = i; }
    }
    long bestsz = -1;
    for (int i = 0; i < n_in; i++) {
        if (i == iw1 || i == iw2 || i == irw || i == ib1 || i == ib2) continue;
        if ((long)in_sizes[i] > bestsz) { bestsz = in_sizes[i]; ix = i; }
    }
    if (ix < 0 || iw1 < 0 || ib1 < 0 || iw2 < 0 || ib2 < 0 || irw < 0) {
        ix = 0; iw1 = 1; ib1 = 2; iw2 = 3; ib2 = 4; irw = 5;
    }
    const void* x  = d_in[ix];
    const void* W1 = d_in[iw1];
    const void* b1 = d_in[ib1];
    const void* W2 = d_in[iw2];
    const void* b2 = d_in[ib2];
    const void* rw = d_in[irw];
    const int B = in_sizes[ix] / 784;
    float* out = (float*)d_out;

    // ---- ws layout (byte offsets, all 16B-aligned) ----
    char* base = (char*)d_ws;
    size_t off = 0;
    float* h1u  = (float*)(base + off); off += (size_t)B * 2400;       // B*600 f32
    float* b1f  = (float*)(base + off); off += 2560;                   // 640 f32
    u32*  flags = (u32*)(base + off);   off += 32;                     // 8 u32
    bfu*   Wt   = (bfu*)(base + off);   off += 1024000;                // 640*800 bf16
    bfu*   xb   = (bfu*)(base + off);   off += (size_t)B * 1600;       // B*800 bf16
    bfu*   rwb  = (bfu*)(base + off);   off += 192000;                 // 96000 bf16 (fallback)
    size_t fb_bytes = off;
    bfu*   rwn  = (bfu*)(base + off);   off += 307200;                 // 30*160*32 bf16
    float* W2t  = (float*)(base + off); off += 48000;                  // 30*20*20 f32
    float* b2f  = (float*)(base + off); off += 2560;                   // 640 f32
    bfu*   pri  = (bfu*)(base + off);   off += (size_t)B * 9600;       // B*4800 bf16
    size_t main_bytes = off;

    const int mode = (ws_size >= main_bytes) ? 0 : 1;   // fixed per-call -> graph-safe
    const int prep_total = B * 200 + 128000 + 640
                         + (mode == 0 ? (153600 + 12000 + 640) : 96000);

    prep_all<<<(prep_total + 255) / 256, 256, 0, stream>>>(x, W1, b1, W2, b2, rw,
                                                           xb, Wt, b1f, rwb, rwn,
                                                           W2t, b2f, flags, B, mode);
    k1n<<<dim3((B + 63) / 64, 10), 128, 0, stream>>>(xb, Wt, b1f, h1u, B, mode == 0 ? 1 : 0);
    if (mode == 0) {
        k2w<<<dim3((B + 127) / 128, 30), 256, 0, stream>>>(h1u, W2t, b2f, rwn, pri, B);
        k3w<<<(B + 1) / 2, 320, 0, stream>>>(pri, out, B);
    } else {
        (void)fb_bytes;
        k2s<<<(B * 30 + 255) / 256, 256, 0, stream>>>(h1u, W2, b2, h1u, flags, B * 30);
        k3y2<<<(B + 3) / 4, 640, 0, stream>>>(h1u, rwb, out, B);
    }
}

// Round 11
// 163.162 us; speedup vs baseline: 1.0610x; 1.0179x over previous
//
#include <hip/hip_runtime.h>

// B(derived), IN_DIM=784, NUM_NETS=30, N_NODES=20, NUM_OUT=10, DIM_OUT=16, NUM_ITER=3
// R25: re-anchor at best-measured config (R22 @163.5us). k1n (R24, BM=64/128thr) was
// -2.6us vs R22's k1m (BM=128/256thr): halved per-block waves weakened barrier overlap
// and doubled Wt-panel LDS staging. Restored R22 k1m verbatim. Kept R24's validated
// pieces: prep w/ folded dtype-detect + flags publish (no detect launch), mode-split
// rwb/rwn sections; k2w fused u+priors MFMA w/ coalesced n-major pri store (R21);
// k3w routing w/ LDS-broadcast allgather (R20/21). Fallback k2s+k3y2 unchanged.

typedef unsigned short bfu;
typedef unsigned int u32;
typedef __attribute__((ext_vector_type(8))) short short8;
typedef __attribute__((ext_vector_type(4))) float floatx4;

__device__ __forceinline__ float bf2f(bfu u) { union { u32 i; float f; } v; v.i = ((u32)u) << 16; return v.f; }
__device__ __forceinline__ float lo2f(u32 w) { union { u32 i; float f; } v; v.i = w << 16; return v.f; }
__device__ __forceinline__ float hi2f(u32 w) { union { u32 i; float f; } v; v.i = w & 0xffff0000u; return v.f; }
__device__ __forceinline__ float ldf(const void* p, int idx, bool b16) {
    return b16 ? bf2f(((const bfu*)p)[idx]) : ((const float*)p)[idx];
}
__device__ __forceinline__ bfu f2bf(float f) {   // RNE
    u32 u = __float_as_uint(f);
    return (bfu)((u + 0x7FFFu + ((u >> 16) & 1u)) >> 16);
}
__device__ __forceinline__ void unpack8(uint4 q, float* dst) {
    dst[0] = lo2f(q.x); dst[1] = hi2f(q.x);
    dst[2] = lo2f(q.y); dst[3] = hi2f(q.y);
    dst[4] = lo2f(q.z); dst[5] = hi2f(q.z);
    dst[6] = lo2f(q.w); dst[7] = hi2f(q.w);
}
__device__ __forceinline__ u32 detect_one(const u32* p) {
    int c = 0;
    for (int i = 0; i < 64; i++) {
        u32 e = (p[i] >> 7) & 0xFF;
        c += (e >= 64 && e <= 140) ? 1 : 0;
    }
    return (c >= 48) ? 1u : 0u;
}

// ---- prep_all (validated R24): xb4 | Wt4 | b1f | (rwn|W2t|b2f if mode==0 else rwb);
//      self-detecting; block 0 publishes flags (fallback k2s). ----
__global__ void prep_all(const void* x, const void* W1, const void* b1,
                         const void* W2, const void* b2, const void* rw,
                         bfu* __restrict__ xb, bfu* __restrict__ Wt,
                         float* __restrict__ b1f, bfu* __restrict__ rwb,
                         bfu* __restrict__ rwn, float* __restrict__ W2t,
                         float* __restrict__ b2f,
                         u32* __restrict__ flags_g, int B, int mode) {
    __shared__ u32 flg[6];
    {
        const int t = threadIdx.x;
        if (t < 6) {
            const u32* p = (t == 0) ? (const u32*)x : (t == 1) ? (const u32*)W1
                         : (t == 2) ? (const u32*)b1 : (t == 3) ? (const u32*)W2
                         : (t == 4) ? (const u32*)b2 : (const u32*)rw;
            flg[t] = detect_one(p);
        }
    }
    __syncthreads();
    if (blockIdx.x == 0 && threadIdx.x < 6) flags_g[threadIdx.x] = flg[threadIdx.x];

    const int idx = blockIdx.x * 256 + threadIdx.x;
    const int nxb4 = B * 200;
    if (idx < nxb4) {                                  // xb[B][800] bf16, 4/thread
        const bool b16 = flg[0] != 0;
        int b = idx / 200, kk = (idx - b * 200) * 4;
        ushort4 w;
        if (kk < 784) {                                // 784%4==0: chunks never straddle
            int src = b * 784 + kk;
            if (b16) {
                w = *(const ushort4*)((const bfu*)x + src);
            } else {
                float4 f = *(const float4*)((const float*)x + src);
                w.x = f2bf(f.x); w.y = f2bf(f.y); w.z = f2bf(f.z); w.w = f2bf(f.w);
            }
        } else { w.x = 0; w.y = 0; w.z = 0; w.w = 0; }
        *(ushort4*)(xb + b * 800 + kk) = w;
        return;
    }
    int i2 = idx - nxb4;
    if (i2 < 128000) {                                 // Wt[c][k] bf16, 4/thread
        const bool wb = flg[1] != 0;
        int c = i2 / 200, k = (i2 - c * 200) * 4;
        ushort4 w; w.x = 0; w.y = 0; w.z = 0; w.w = 0;
        if (c < 600 && k < 784) {
            int nn = c / 20, o = c - nn * 20;
            int src = nn * 15680 + k * 20 + o;         // k-stride 20
            if (wb) {
                const bfu* p = (const bfu*)W1;
                w.x = p[src]; w.y = p[src + 20]; w.z = p[src + 40]; w.w = p[src + 60];
            } else {
                const float* p = (const float*)W1;
                w.x = f2bf(p[src]); w.y = f2bf(p[src + 20]);
                w.z = f2bf(p[src + 40]); w.w = f2bf(p[src + 60]);
            }
        }
        *(ushort4*)(Wt + c * 800 + k) = w;
        return;
    }
    i2 -= 128000;
    if (i2 < 640) {                                    // b1f fp32
        b1f[i2] = (i2 < 600) ? ldf(b1, i2, flg[2] != 0) : 0.f;
        return;
    }
    i2 -= 640;
    if (mode == 0) {
        if (i2 < 153600) {                             // rwn[n][col=o*16+k][dd<32] bf16, K-pad
            const bool rb = flg[5] != 0;
            int dd = i2 % 32;
            int col = (i2 / 32) % 160;
            int n = i2 / 5120;
            bfu v = 0;
            if (dd < 20) {
                int o = col / 16, kk = col % 16;
                int src = o * 9600 + n * 320 + dd * 16 + kk;
                v = rb ? ((const bfu*)rw)[src] : f2bf(((const float*)rw)[src]);
            }
            rwn[i2] = v;
            return;
        }
        i2 -= 153600;
        if (i2 < 12000) {                              // W2t[n][e][d] fp32 = W2[n][d][e]
            int d = i2 % 20;
            int e = (i2 / 20) % 20;
            int n = i2 / 400;
            W2t[i2] = ldf(W2, n * 400 + d * 20 + e, flg[3] != 0);
            return;
        }
        i2 -= 12000;
        if (i2 < 640) {                                // b2f fp32
            b2f[i2] = (i2 < 600) ? ldf(b2, i2, flg[4] != 0) : 0.f;
        }
    } else {
        if (i2 < 96000) {                              // rwb[o][n][k][d] bf16 (fallback k3y2)
            const bool rb = flg[5] != 0;
            int d = i2 % 20;
            int k = (i2 / 20) % 16;
            int n = (i2 / 320) % 30;
            int o = i2 / 9600;
            int src = o * 9600 + n * 320 + d * 16 + k;
            rwb[i2] = rb ? ((const bfu*)rw)[src] : f2bf(((const float*)rw)[src]);
        }
    }
}

// ---------------- K1m: h1 = relu(xb @ Wt^T + b1), bf16 MFMA (validated R22, BM=128) ----------------
// tr==1 (mode 0): h1 [n][b][20], LDS-staged coalesced float4 stores. tr==0: [b][600] direct.
__global__ __launch_bounds__(256, 4) void k1m(const bfu* __restrict__ xb, const bfu* __restrict__ Wt,
                                              const float* __restrict__ b1f,
                                              float* __restrict__ h1, int Btot, int tr) {
    __shared__ __align__(16) char smem[128 * 68 * 4];   // max(As+Bs=27648, ep=34816)
    short* As = (short*)smem;                // [128][72]
    short* Bs = (short*)(smem + 128 * 72 * 2);  // [64][72]
    const int tid = threadIdx.x;
    const int w = tid >> 6, lane = tid & 63;
    const int quad = lane >> 4, fl = lane & 15;
    const int m0 = blockIdx.x * 128, n0 = blockIdx.y * 64;

    floatx4 acc[2][4];
    #pragma unroll
    for (int mi = 0; mi < 2; mi++)
        #pragma unroll
        for (int ni = 0; ni < 4; ni++) acc[mi][ni] = (floatx4){0.f, 0.f, 0.f, 0.f};

    const int arow = tid >> 1, aseg = tid & 1;    // 2 thr/row, 64B each
    const int brow = tid >> 2, bseg = tid & 3;    // 4 thr/row, 32B each
    int agrow = m0 + arow; if (agrow >= Btot) agrow = Btot - 1;
    const bfu* abase = xb + (size_t)agrow * 800 + aseg * 32;
    const bfu* bbase = Wt + (size_t)(n0 + brow) * 800 + bseg * 16;

    // 12 steps of BK=64
    for (int k0 = 0; k0 < 768; k0 += 64) {
        uint4 qa0 = *(const uint4*)(abase + k0);
        uint4 qa1 = *(const uint4*)(abase + k0 + 8);
        uint4 qa2 = *(const uint4*)(abase + k0 + 16);
        uint4 qa3 = *(const uint4*)(abase + k0 + 24);
        uint4 qb0 = *(const uint4*)(bbase + k0);
        uint4 qb1 = *(const uint4*)(bbase + k0 + 8);

        __syncthreads();
        *(uint4*)&As[arow * 72 + aseg * 32 + 0]  = qa0;
        *(uint4*)&As[arow * 72 + aseg * 32 + 8]  = qa1;
        *(uint4*)&As[arow * 72 + aseg * 32 + 16] = qa2;
        *(uint4*)&As[arow * 72 + aseg * 32 + 24] = qa3;
        *(uint4*)&Bs[brow * 72 + bseg * 16 + 0]  = qb0;
        *(uint4*)&Bs[brow * 72 + bseg * 16 + 8]  = qb1;
        __syncthreads();

        short8 af[2][2], bfr[4][2];
        #pragma unroll
        for (int mi = 0; mi < 2; mi++)
            #pragma unroll
            for (int kk = 0; kk < 2; kk++)
                af[mi][kk] = *(const short8*)&As[(w * 32 + mi * 16 + fl) * 72 + kk * 32 + quad * 8];
        #pragma unroll
        for (int ni = 0; ni < 4; ni++)
            #pragma unroll
            for (int kk = 0; kk < 2; kk++)
                bfr[ni][kk] = *(const short8*)&Bs[(ni * 16 + fl) * 72 + kk * 32 + quad * 8];
        #pragma unroll
        for (int kk = 0; kk < 2; kk++)
            #pragma unroll
            for (int mi = 0; mi < 2; mi++)
                #pragma unroll
                for (int ni = 0; ni < 4; ni++)
                    acc[mi][ni] = __builtin_amdgcn_mfma_f32_16x16x32_bf16(af[mi][kk], bfr[ni][kk], acc[mi][ni], 0, 0, 0);
    }

    // tail step: k0=768, 32 wide
    {
        const bfu* at = xb + (size_t)agrow * 800 + 768 + aseg * 16;
        const bfu* bt = Wt + (size_t)(n0 + brow) * 800 + 768 + bseg * 8;
        uint4 qa0 = *(const uint4*)(at);
        uint4 qa1 = *(const uint4*)(at + 8);
        uint4 qb0 = *(const uint4*)(bt);

        __syncthreads();
        *(uint4*)&As[arow * 72 + aseg * 16 + 0] = qa0;
        *(uint4*)&As[arow * 72 + aseg * 16 + 8] = qa1;
        *(uint4*)&Bs[brow * 72 + bseg * 8] = qb0;
        __syncthreads();

        short8 af[2], bfr[4];
        #pragma unroll
        for (int mi = 0; mi < 2; mi++)
            af[mi] = *(const short8*)&As[(w * 32 + mi * 16 + fl) * 72 + quad * 8];
        #pragma unroll
        for (int ni = 0; ni < 4; ni++)
            bfr[ni] = *(const short8*)&Bs[(ni * 16 + fl) * 72 + quad * 8];
        #pragma unroll
        for (int mi = 0; mi < 2; mi++)
            #pragma unroll
            for (int ni = 0; ni < 4; ni++)
                acc[mi][ni] = __builtin_amdgcn_mfma_f32_16x16x32_bf16(af[mi], bfr[ni], acc[mi][ni], 0, 0, 0);
    }

    if (tr) {
        // R22 epilogue: stage bias+relu result to LDS (reuses As/Bs region), then
        // cooperative float4 writes: 8/thread, 80B-contiguous runs in h1n[n][b][20].
        __syncthreads();                       // all waves done reading As/Bs
        float* ep = (float*)smem;              // [128][68]
        #pragma unroll
        for (int mi = 0; mi < 2; mi++) {
            #pragma unroll
            for (int ni = 0; ni < 4; ni++) {
                const int c = n0 + ni * 16 + fl;
                const float bias = b1f[c];     // b1f padded to 640
                #pragma unroll
                for (int r = 0; r < 4; r++)
                    ep[(w * 32 + mi * 16 + quad * 4 + r) * 68 + ni * 16 + fl]
                        = fmaxf(acc[mi][ni][r] + bias, 0.f);
            }
        }
        __syncthreads();
        #pragma unroll
        for (int s = 0; s < 8; s++) {
            const int i = s * 256 + tid;
            const int ml = i >> 4, cq = i & 15;
            const int c = n0 + cq * 4;
            const int m = m0 + ml;
            if (c < 600 && m < Btot) {
                const int cn = c / 20, ce = c - cn * 20;   // 20%4==0: chunk within net
                *(float4*)(h1 + ((size_t)cn * Btot + m) * 20 + ce)
                    = *(const float4*)&ep[ml * 68 + cq * 4];
            }
        }
    } else {
        #pragma unroll
        for (int mi = 0; mi < 2; mi++) {
            #pragma unroll
            for (int ni = 0; ni < 4; ni++) {
                const int c = n0 + ni * 16 + fl;
                #pragma unroll
                for (int r = 0; r < 4; r++) {
                    const int m = m0 + w * 32 + mi * 16 + quad * 4 + r;
                    if (c < 600 && m < Btot)
                        h1[(size_t)m * 600 + c] = fmaxf(acc[mi][ni][r] + b1f[c], 0.f);
                }
            }
        }
    }
}

// ---------------- K2w (main, validated R21): fused u-compute + priors MFMA, coalesced store ----------------
__global__ __launch_bounds__(256) void k2w(const float* __restrict__ h1n,
                                           const float* __restrict__ W2t,
                                           const float* __restrict__ b2f,
                                           const bfu* __restrict__ rwn,
                                           bfu* __restrict__ pri, int Btot) {
    __shared__ short us[128 * 40];
    __shared__ short pst[64 * 168];   // [row_local][160 + 8 pad]
    const int tid = threadIdx.x;
    const int n = blockIdx.y;
    const int b0 = blockIdx.x * 128;

    const int w = tid >> 6, lane = tid & 63;
    const int quad = lane >> 4, fl = lane & 15;
    short8 bfr[10];
    #pragma unroll
    for (int nj = 0; nj < 10; nj++)
        bfr[nj] = *(const short8*)(rwn + ((size_t)n * 160 + nj * 16 + fl) * 32 + quad * 8);

    {   // ---- phase 1: u for rows b0..b0+127 ----
        const int row = tid >> 1, half = tid & 1;
        int br = b0 + row; if (br >= Btot) br = Btot - 1;
        float h[20];
        const float* hp = h1n + ((size_t)n * Btot + br) * 20;
        #pragma unroll
        for (int d4 = 0; d4 < 20; d4 += 4) {
            float4 v = *(const float4*)(hp + d4);
            h[d4] = v.x; h[d4 + 1] = v.y; h[d4 + 2] = v.z; h[d4 + 3] = v.w;
        }
        const float* wn = W2t + n * 400;
        const float* bn = b2f + n * 20;
        float o[10], sq = 0.f;
        #pragma unroll
        for (int i = 0; i < 10; i++) {
            const int e = 2 * i + half;
            float acc = bn[e];
            #pragma unroll
            for (int d = 0; d < 20; d++) acc += h[d] * wn[e * 20 + d];
            acc = fmaxf(acc, 0.f);
            o[i] = acc;
            sq += acc * acc;
        }
        sq += __shfl_xor(sq, 1);
        float sc = (sq > 0.f) ? sqrtf(sq) / (1.f + sq) : 0.f;
        #pragma unroll
        for (int i = 0; i < 10; i++)
            us[row * 40 + 2 * i + half] = (short)f2bf(o[i] * sc);
        #pragma unroll
        for (int i = 10; i < 16; i++)
            us[row * 40 + 2 * i + half] = 0;
    }
    __syncthreads();

    // ---- phase 2: per-mi MFMA -> LDS stage -> coalesced write ----
    #pragma unroll
    for (int mi = 0; mi < 2; mi++) {
        short8 af = *(const short8*)&us[(w * 32 + mi * 16 + fl) * 40 + quad * 8];
        #pragma unroll
        for (int nj = 0; nj < 10; nj++) {
            floatx4 acc = (floatx4){0.f, 0.f, 0.f, 0.f};
            acc = __builtin_amdgcn_mfma_f32_16x16x32_bf16(af, bfr[nj], acc, 0, 0, 0);
            #pragma unroll
            for (int r = 0; r < 4; r++)
                pst[(w * 16 + quad * 4 + r) * 168 + nj * 16 + fl] = (short)f2bf(acc[r]);
        }
        __syncthreads();
        #pragma unroll
        for (int s = 0; s < 5; s++) {
            int i = s * 256 + tid;
            int rl = i / 20, seg = i - rl * 20;
            int row = b0 + (rl >> 4) * 32 + mi * 16 + (rl & 15);
            if (row < Btot)
                *(uint4*)(pri + (size_t)row * 4800 + n * 160 + seg * 8)
                    = *(const uint4*)&pst[rl * 168 + seg * 8];
        }
        __syncthreads();
    }
}

// ---------------- K2 core (fallback path, validated math) ----------------
__device__ __forceinline__ void k2_core(const float* hp, const float* wn, const float* bn,
                                        float* o, float& sc) {
    float h[20];
    #pragma unroll
    for (int d4 = 0; d4 < 20; d4 += 4) {
        float4 v = *(const float4*)(hp + d4);
        h[d4] = v.x; h[d4 + 1] = v.y; h[d4 + 2] = v.z; h[d4 + 3] = v.w;
    }
    float sq = 0.f;
    #pragma unroll
    for (int e = 0; e < 20; e++) {
        float acc = bn[e];
        #pragma unroll
        for (int d = 0; d < 20; d++) acc += h[d] * wn[d * 20 + e];
        acc = fmaxf(acc, 0.f);
        o[e] = acc;
        sq += acc * acc;
    }
    sc = (sq > 0.f) ? sqrtf(sq) / (1.f + sq) : 0.f;
}

// K2s (fallback, validated): u fp32 in place; flags written by prep_all block 0
__global__ __launch_bounds__(256) void k2s(const float* h1, const void* W2, const void* b2,
                                           float* u, const u32* flags, int total) {
    __shared__ float W2s[12000];
    __shared__ float b2s[600];
    const bool wb = flags[3] != 0, bb = flags[4] != 0;
    const int tid = threadIdx.x;
    for (int i = tid; i < 12000; i += 256) W2s[i] = ldf(W2, i, wb);
    for (int i = tid; i < 600; i += 256) b2s[i] = ldf(b2, i, bb);
    __syncthreads();

    int t = blockIdx.x * 256 + tid;
    if (t >= total) return;
    const int b = t / 30, n = t - b * 30;
    float o[20], sc;
    k2_core(h1 + (size_t)b * 600 + n * 20, &W2s[n * 400], &b2s[n * 20], o, sc);
    float* up = u + (size_t)b * 600 + n * 20;
    #pragma unroll
    for (int e4 = 0; e4 < 20; e4 += 4) {
        float4 v;
        v.x = o[e4] * sc; v.y = o[e4 + 1] * sc; v.z = o[e4 + 2] * sc; v.w = o[e4 + 3] * sc;
        *(float4*)(up + e4) = v;
    }
}

// ---------------- K3w: routing, LDS-broadcast allgather, n-major pri (validated R21) ----------------
__global__ __launch_bounds__(320, 4) void k3w(const bfu* __restrict__ pri_buf,
                                              float* __restrict__ out, int Btot) {
    __shared__ float L[2][300];
    __shared__ float P[2][300];
    __shared__ float S[2][200];   // [g][o*20 + k]
    const int tid = threadIdx.x;
    const int g = tid / 160, r = tid - g * 160;
    const int o = r >> 4, j = r & 15;
    const int b0 = blockIdx.x * 2;
    int bb = b0 + g; if (bb >= Btot) bb = Btot - 1;

    const int n0 = 2 * j, n1 = n0 + 1;
    float p0[16], p1[16];
    if (j < 15) {
        const bfu* pb = pri_buf + (size_t)bb * 4800 + n0 * 160 + o * 16;
        uint4 q0 = *(const uint4*)(pb);          // n0 k0..7
        uint4 q1 = *(const uint4*)(pb + 8);      // n0 k8..15
        uint4 q2 = *(const uint4*)(pb + 160);    // n1 k0..7
        uint4 q3 = *(const uint4*)(pb + 168);    // n1 k8..15
        unpack8(q0, p0); unpack8(q1, p0 + 8);
        unpack8(q2, p1); unpack8(q3, p1 + 8);
    } else {
        #pragma unroll
        for (int i = 0; i < 16; i++) { p0[i] = 0.f; p1[i] = 0.f; }
    }

    float L0 = 0.f, L1 = 0.f;
    float v = 0.f;
    #pragma unroll
    for (int it = 0; it < 3; it++) {
        float P0, P1;
        if (it == 0) {
            P0 = 0.1f; P1 = 0.1f;              // softmax(zeros) over 10 outputs
        } else {
            if (r < 30) {                       // dedicated softmax over o for net r
                float l[10];
                #pragma unroll
                for (int oo = 0; oo < 10; oo++) l[oo] = L[g][r * 10 + oo];
                float mx = l[0];
                #pragma unroll
                for (int oo = 1; oo < 10; oo++) mx = fmaxf(mx, l[oo]);
                float den = 0.f;
                #pragma unroll
                for (int oo = 0; oo < 10; oo++) { l[oo] = __expf(l[oo] - mx); den += l[oo]; }
                float inv = 1.f / den;
                #pragma unroll
                for (int oo = 0; oo < 10; oo++) P[g][r * 10 + oo] = l[oo] * inv;
            }
            __syncthreads();
            P0 = (j < 15) ? P[g][n0 * 10 + o] : 0.f;
            P1 = (j < 15) ? P[g][n1 * 10 + o] : 0.f;
        }

        float t[16];
        #pragma unroll
        for (int i = 0; i < 16; i++) t[i] = P0 * p0[i] + P1 * p1[i];

        // 16-lane transpose-reduce: lane j ends with s[k=j] (15 shuffles)
        #pragma unroll
        for (int i = 0; i < 8; i++) {
            float send = (j & 8) ? t[i] : t[i + 8];
            float recv = __shfl_xor(send, 8, 16);
            t[i] = ((j & 8) ? t[i + 8] : t[i]) + recv;
        }
        #pragma unroll
        for (int i = 0; i < 4; i++) {
            float send = (j & 4) ? t[i] : t[i + 4];
            float recv = __shfl_xor(send, 4, 16);
            t[i] = ((j & 4) ? t[i + 4] : t[i]) + recv;
        }
        #pragma unroll
        for (int i = 0; i < 2; i++) {
            float send = (j & 2) ? t[i] : t[i + 2];
            float recv = __shfl_xor(send, 2, 16);
            t[i] = ((j & 2) ? t[i + 2] : t[i]) + recv;
        }
        {
            float send = (j & 1) ? t[0] : t[1];
            float recv = __shfl_xor(send, 1, 16);
            t[0] = ((j & 1) ? t[1] : t[0]) + recv;
        }
        float s = t[0];                         // s[o, k=j]

        if (it < 2) {
            // wave-internal LDS allgather: write s, read back the o-group's 16 values
            S[g][o * 20 + j] = s;
            float4 s0 = *(const float4*)&S[g][o * 20 + 0];
            float4 s1 = *(const float4*)&S[g][o * 20 + 4];
            float4 s2 = *(const float4*)&S[g][o * 20 + 8];
            float4 s3 = *(const float4*)&S[g][o * 20 + 12];
            float sf[16];
            sf[0] = s0.x;  sf[1] = s0.y;  sf[2] = s0.z;  sf[3] = s0.w;
            sf[4] = s1.x;  sf[5] = s1.y;  sf[6] = s1.z;  sf[7] = s1.w;
            sf[8] = s2.x;  sf[9] = s2.y;  sf[10] = s2.z; sf[11] = s2.w;
            sf[12] = s3.x; sf[13] = s3.y; sf[14] = s3.z; sf[15] = s3.w;
            float q = 0.f;
            #pragma unroll
            for (int k = 0; k < 16; k++) q += sf[k] * sf[k];
            float scale = sqrtf(q) / (1.f + q);
            v = s * scale;
            float d0 = 0.f, d1 = 0.f;
            #pragma unroll
            for (int k = 0; k < 16; k++) {
                float vk = sf[k] * scale;
                d0 += p0[k] * vk;
                d1 += p1[k] * vk;
            }
            L0 += d0; L1 += d1;
            if (j < 15) {
                L[g][n0 * 10 + o] = L0;
                L[g][n1 * 10 + o] = L1;
            }
            __syncthreads();
        } else {
            float q = s * s;
            q += __shfl_xor(q, 1, 16);
            q += __shfl_xor(q, 2, 16);
            q += __shfl_xor(q, 4, 16);
            q += __shfl_xor(q, 8, 16);
            v = s * sqrtf(q) / (1.f + q);
        }
    }
    if ((b0 + g) < Btot) out[(size_t)(b0 + g) * 160 + r] = v;
}

// ---------------- K3y2 (fallback, validated @202us) ----------------
__global__ __launch_bounds__(640, 2) void k3y2(const float* __restrict__ u,
                                               const bfu* __restrict__ rwb,
                                               float* __restrict__ out, int Btot) {
    __shared__ float US[4][600];
    __shared__ float L[4][300];
    __shared__ float P[4][300];
    const int tid = threadIdx.x;
    const int g = tid / 160, r = tid - g * 160;
    const int o = r >> 4, k = r & 15;
    const int b0 = blockIdx.x * 4;

    {
        const int nf4 = 150;
        for (int i = tid; i < 4 * nf4; i += 640) {
            int gg = i / nf4, j = i - gg * nf4;
            int bb = b0 + gg; if (bb >= Btot) bb = Btot - 1;
            *(float4*)&US[gg][j * 4] = *(const float4*)(u + (size_t)bb * 600 + j * 4);
        }
        for (int i = tid; i < 1200; i += 640) L[i / 300][i % 300] = 0.f;
    }
    __syncthreads();

    float pri[30];
    const bfu* rp = rwb + o * 9600 + k * 20;
    #pragma unroll 2
    for (int n = 0; n < 30; n++) {
        const uint2* rq = (const uint2*)(rp + n * 320);
        float a = 0.f;
        #pragma unroll
        for (int jj = 0; jj < 5; jj++) {
            uint2 w = rq[jj];
            float4 uu = *(const float4*)&US[g][n * 20 + jj * 4];
            a += lo2f(w.x) * uu.x + hi2f(w.x) * uu.y + lo2f(w.y) * uu.z + hi2f(w.y) * uu.w;
        }
        pri[n] = a;
    }

    float v = 0.f;
    for (int it = 0; it < 3; it++) {
        if (r < 30) {
            const int n = r;
            float mx = L[g][n * 10];
            #pragma unroll
            for (int oo = 1; oo < 10; oo++) mx = fmaxf(mx, L[g][n * 10 + oo]);
            float e[10], den = 0.f;
            #pragma unroll
            for (int oo = 0; oo < 10; oo++) { e[oo] = __expf(L[g][n * 10 + oo] - mx); den += e[oo]; }
            float inv = 1.f / den;
            #pragma unroll
            for (int oo = 0; oo < 10; oo++) P[g][n * 10 + oo] = e[oo] * inv;
        }
        __syncthreads();
        float s = 0.f;
        #pragma unroll
        for (int n = 0; n < 30; n++) s += P[g][n * 10 + o] * pri[n];
        float q = s * s;
        q += __shfl_xor(q, 1, 16);
        q += __shfl_xor(q, 2, 16);
        q += __shfl_xor(q, 4, 16);
        q += __shfl_xor(q, 8, 16);
        v = s * sqrtf(q) / (1.f + q);
        if (it < 2) {
            #pragma unroll 5
            for (int n = 0; n < 30; n++) {
                float t = pri[n] * v;
                t += __shfl_xor(t, 1, 16);
                t += __shfl_xor(t, 2, 16);
                t += __shfl_xor(t, 4, 16);
                t += __shfl_xor(t, 8, 16);
                if (k == 0) L[g][n * 10 + o] += t;
            }
            __syncthreads();
        }
    }
    if ((b0 + g) < Btot) out[(size_t)(b0 + g) * 160 + r] = v;
}

extern "C" void kernel_launch(void* const* d_in, const int* in_sizes, int n_in,
                              void* d_out, int out_size, void* d_ws, size_t ws_size,
                              hipStream_t stream) {
    // ---- size-based input matching (validated) ----
    int ix = -1, iw1 = -1, ib1 = -1, iw2 = -1, ib2 = -1, irw = -1;
    for (int i = 0; i < n_in; i++) {
        int s = in_sizes[i];
        if (s == 470400 && iw1 < 0) iw1 = i;
        else if (s == 12000 && iw2 < 0) iw2 = i;
        else if (s == 96000 && irw < 0) irw = i;
        else if (s == 600) { if (ib1 < 0) ib1 = i; else if (ib2 < 0) ib2 = i; }
    }
    long bestsz = -1;
    for (int i = 0; i < n_in; i++) {
        if (i == iw1 || i == iw2 || i == irw || i == ib1 || i == ib2) continue;
        if ((long)in_sizes[i] > bestsz) { bestsz = in_sizes[i]; ix = i; }
    }
    if (ix < 0 || iw1 < 0 || ib1 < 0 || iw2 < 0 || ib2 < 0 || irw < 0) {
        ix = 0; iw1 = 1; ib1 = 2; iw2 = 3; ib2 = 4; irw = 5;
    }
    const void* x  = d_in[ix];
    const void* W1 = d_in[iw1];
    const void* b1 = d_in[ib1];
    const void* W2 = d_in[iw2];
    const void* b2 = d_in[ib2];
    const void* rw = d_in[irw];
    const int B = in_sizes[ix] / 784;
    float* out = (float*)d_out;

    // ---- ws layout (byte offsets, all 16B-aligned) ----
    char* base = (char*)d_ws;
    size_t off = 0;
    float* h1u  = (float*)(base + off); off += (size_t)B * 2400;       // B*600 f32
    float* b1f  = (float*)(base + off); off += 2560;                   // 640 f32
    u32*  flags = (u32*)(base + off);   off += 32;                     // 8 u32
    bfu*   Wt   = (bfu*)(base + off);   off += 1024000;                // 640*800 bf16
    bfu*   xb   = (bfu*)(base + off);   off += (size_t)B * 1600;       // B*800 bf16
    bfu*   rwb  = (bfu*)(base + off);   off += 192000;                 // 96000 bf16 (fallback)
    size_t fb_bytes = off;
    bfu*   rwn  = (bfu*)(base + off);   off += 307200;                 // 30*160*32 bf16
    float* W2t  = (float*)(base + off); off += 48000;                  // 30*20*20 f32
    float* b2f  = (float*)(base + off); off += 2560;                   // 640 f32
    bfu*   pri  = (bfu*)(base + off);   off += (size_t)B * 9600;       // B*4800 bf16
    size_t main_bytes = off;

    const int mode = (ws_size >= main_bytes) ? 0 : 1;   // fixed per-call -> graph-safe
    const int prep_total = B * 200 + 128000 + 640
                         + (mode == 0 ? (153600 + 12000 + 640) : 96000);

    prep_all<<<(prep_total + 255) / 256, 256, 0, stream>>>(x, W1, b1, W2, b2, rw,
                                                           xb, Wt, b1f, rwb, rwn,
                                                           W2t, b2f, flags, B, mode);
    k1m<<<dim3((B + 127) / 128, 10), 256, 0, stream>>>(xb, Wt, b1f, h1u, B, mode == 0 ? 1 : 0);
    if (mode == 0) {
        k2w<<<dim3((B + 127) / 128, 30), 256, 0, stream>>>(h1u, W2t, b2f, rwn, pri, B);
        k3w<<<(B + 1) / 2, 320, 0, stream>>>(pri, out, B);
    } else {
        (void)fb_bytes;
        k2s<<<(B * 30 + 255) / 256, 256, 0, stream>>>(h1u, W2, b2, h1u, flags, B * 30);
        k3y2<<<(B + 3) / 4, 640, 0, stream>>>(h1u, rwb, out, B);
    }
}